// Round 3
// baseline (314.149 us; speedup 1.0000x reference)
//
#include <hip/hip_runtime.h>

#define NN    50000   // nodes
#define NHE   50000   // hyperedges
#define NEDGE 320000  // incidence pairs
#define DD    256     // feature dim

#define SB    1024                    // scan elements per block
#define NBLK  ((NN + SB - 1) / SB)    // blocks per segment (NN == NHE) = 49
#define CNTB  ((NEDGE / 4 + 255) / 256)  // 313 blocks for ILP=4 edge kernels

typedef float f32x4 __attribute__((ext_vector_type(4)));
typedef short short8 __attribute__((ext_vector_type(8)));

// ---- bf16 helpers (RTNE) ----
static __device__ __forceinline__ unsigned short f2b(float f) {
    union { float f; unsigned u; } c; c.f = f;
    unsigned u = c.u;
    u += 0x7fffu + ((u >> 16) & 1u);
    return (unsigned short)(u >> 16);
}
static __device__ __forceinline__ float b2f_lo(unsigned v) {
    union { unsigned u; float f; } c; c.u = v << 16; return c.f;
}
static __device__ __forceinline__ float b2f_hi(unsigned v) {
    union { unsigned u; float f; } c; c.u = v & 0xffff0000u; return c.f;
}
static __device__ __forceinline__ unsigned pack2(float a, float b) {
    return (unsigned)f2b(a) | ((unsigned)f2b(b) << 16);
}

// async 16B global -> LDS (linear dest: wave-uniform base + lane*16)
static __device__ __forceinline__ void glds16(const unsigned short* g, unsigned short* l) {
    __builtin_amdgcn_global_load_lds((const __attribute__((address_space(1))) unsigned int*)g,
                                     (__attribute__((address_space(3))) unsigned int*)l,
                                     16, 0, 0);
}

// ---------------- CSR build ----------------
// count + rank capture fused with fp32->bf16 weight conversion (independent
// work sharing one dispatch). atomicAdd's return value IS the edge's slot
// within its bucket -> fill pass needs no atomics. ILP=4 edges/thread.
__global__ __launch_bounds__(256) void k_count_cvt(const int* __restrict__ src,
                                                   const int* __restrict__ he,
                                                   int* __restrict__ cnt_n,
                                                   int* __restrict__ cnt_e,
                                                   int* __restrict__ rank_n,
                                                   int* __restrict__ rank_e,
                                                   const float* __restrict__ w1,
                                                   const float* __restrict__ w2,
                                                   unsigned short* __restrict__ o1,
                                                   unsigned short* __restrict__ o2) {
    int bx = blockIdx.x;
    if (bx >= CNTB) {   // 128 trailing blocks: weight conversion
        int t = (bx - CNTB) * 256 + threadIdx.x;   // 0 .. 32767
        const int n4 = DD * DD / 4;
        const float* s = (t < n4) ? w1 : w2;
        unsigned short* d = (t < n4) ? o1 : o2;
        int i = (t < n4) ? t : t - n4;
        float4 v = ((const float4*)s)[i];
        uint2 o;
        o.x = pack2(v.x, v.y);
        o.y = pack2(v.z, v.w);
        ((uint2*)d)[i] = o;
        return;
    }
    int t  = bx * 256 + threadIdx.x;
    int e0 = t * 4;
    if (e0 >= NEDGE) return;
    int4 s = *(const int4*)(src + e0);
    int4 h = *(const int4*)(he + e0);
    int4 rn, re;
    rn.x = atomicAdd(&cnt_n[s.x], 1);
    rn.y = atomicAdd(&cnt_n[s.y], 1);
    rn.z = atomicAdd(&cnt_n[s.z], 1);
    rn.w = atomicAdd(&cnt_n[s.w], 1);
    re.x = atomicAdd(&cnt_e[h.x], 1);
    re.y = atomicAdd(&cnt_e[h.y], 1);
    re.z = atomicAdd(&cnt_e[h.z], 1);
    re.w = atomicAdd(&cnt_e[h.w], 1);
    *(int4*)(rank_n + e0) = rn;
    *(int4*)(rank_e + e0) = re;
}

__global__ __launch_bounds__(256) void k_scan_a(const int* __restrict__ cnt_n,
                                                const int* __restrict__ cnt_e,
                                                int* __restrict__ bsum) {
    int b   = blockIdx.x;            // 0 .. 2*NBLK-1
    int seg = b / NBLK, lb = b % NBLK;
    const int* cnt = seg ? cnt_e : cnt_n;
    int t = threadIdx.x;
    int idx = lb * SB + t * 4;
    int s = 0;
#pragma unroll
    for (int j = 0; j < 4; ++j)
        if (idx + j < NN) s += cnt[idx + j];
    __shared__ int red[256];
    red[t] = s;
    __syncthreads();
    for (int o = 128; o > 0; o >>= 1) {
        if (t < o) red[t] += red[t + o];
        __syncthreads();
    }
    if (t == 0) bsum[b] = red[0];
}

// block-level exclusive scan; each block derives its own base from the 49
// per-block sums (removes the separate sequential-scan dispatch)
__global__ __launch_bounds__(256) void k_scan_c(const int* __restrict__ cnt_n,
                                                const int* __restrict__ cnt_e,
                                                const int* __restrict__ bsum,
                                                int* __restrict__ off_n,
                                                int* __restrict__ off_e) {
    int b   = blockIdx.x;
    int seg = b / NBLK, lb = b % NBLK;
    const int* cnt = seg ? cnt_e : cnt_n;
    int* off = seg ? off_e : off_n;
    int t = threadIdx.x;
    __shared__ int sb[NBLK];
    __shared__ int binfo[2];   // [0]=base for this block, [1]=segment total
    if (t < NBLK) sb[t] = bsum[seg * NBLK + t];
    __syncthreads();
    if (t == 0) {
        int base = 0, tot = 0;
        for (int j = 0; j < NBLK; ++j) { if (j < lb) base += sb[j]; tot += sb[j]; }
        binfo[0] = base; binfo[1] = tot;
    }
    int idx = lb * SB + t * 4;
    int v[4];
    int tsum = 0;
#pragma unroll
    for (int j = 0; j < 4; ++j) {
        v[j] = (idx + j < NN) ? cnt[idx + j] : 0;
        tsum += v[j];
    }
    __shared__ int sc[256];
    sc[t] = tsum;
    __syncthreads();
    for (int o = 1; o < 256; o <<= 1) {
        int val = (t >= o) ? sc[t - o] : 0;
        __syncthreads();
        sc[t] += val;
        __syncthreads();
    }
    int p = binfo[0] + sc[t] - tsum;
#pragma unroll
    for (int j = 0; j < 4; ++j) {
        if (idx + j < NN) off[idx + j] = p;
        p += v[j];
    }
    if (b == 0 && t == 0) off_n[NN] = binfo[1];
    if (b == NBLK && t == 0) off_e[NHE] = binfo[1];
}

// ---------------- bf16 MFMA GEMM body: C[m,n] = sum_k A[m,k]*W[n,k] ----------
// 128x128 tile, BK=32, 256 thr = 4 waves as 2x2, wave tile 64x64. B staged via
// global_load_lds w=16 (linear LDS dest, XOR swizzle folded into the GLOBAL
// source address); ds_read applies the same swizzle.
template <bool A32>
static __device__ __forceinline__ void gemm128_body(const void* __restrict__ Av,
                                                    const unsigned short* __restrict__ Wb,
                                                    unsigned short* __restrict__ Cb,
                                                    int M, int m0, int n0) {
    __shared__ __align__(16) unsigned short As[128 * 32];
    __shared__ __align__(16) unsigned short Bs[128 * 32];
    const int t    = threadIdx.x;
    const int lane = t & 63;
    const int wave = t >> 6;
    const int wm   = (wave >> 1) * 64;
    const int wn   = (wave & 1) * 64;
    const int fr   = lane & 15;
    const int fq   = lane >> 4;

    f32x4 acc[4][4] = {};

    const int rl0 = wave * 32 + (lane >> 2);
    const int ar = t >> 1;
    const int ah = t & 1;

    for (int k0 = 0; k0 < DD; k0 += 32) {
        __syncthreads();   // protect previous iteration's LDS readers
#pragma unroll
        for (int q = 0; q < 2; ++q) {
            int rl = rl0 + q * 16;
            int c  = (lane & 3) ^ (rl & 3);   // pre-swizzled source chunk
            glds16(Wb + (size_t)(n0 + rl) * DD + k0 + c * 8,
                   Bs + (size_t)(wave * 32 + q * 16) * 32);
        }
        if (A32) {
            int gr = m0 + ar; if (gr >= M) gr = M - 1;
            const float* p = (const float*)Av + (size_t)gr * DD + k0 + ah * 16;
            float4 f0 = ((const float4*)p)[0];
            float4 f1 = ((const float4*)p)[1];
            float4 f2 = ((const float4*)p)[2];
            float4 f3 = ((const float4*)p)[3];
            uint4 u0, u1;
            u0.x = pack2(f0.x, f0.y); u0.y = pack2(f0.z, f0.w);
            u0.z = pack2(f1.x, f1.y); u0.w = pack2(f1.z, f1.w);
            u1.x = pack2(f2.x, f2.y); u1.y = pack2(f2.z, f2.w);
            u1.z = pack2(f3.x, f3.y); u1.w = pack2(f3.z, f3.w);
            int p0 = (2 * ah) ^ (ar & 3);
            int p1 = (2 * ah + 1) ^ (ar & 3);
            *(uint4*)(As + ar * 32 + p0 * 8) = u0;
            *(uint4*)(As + ar * 32 + p1 * 8) = u1;
        } else {
#pragma unroll
            for (int q = 0; q < 2; ++q) {
                int rl = rl0 + q * 16;
                int gr = m0 + rl; if (gr >= M) gr = M - 1;
                int c  = (lane & 3) ^ (rl & 3);
                glds16((const unsigned short*)Av + (size_t)gr * DD + k0 + c * 8,
                       As + (size_t)(wave * 32 + q * 16) * 32);
            }
        }
        __syncthreads();   // barrier drains vmcnt (glds) + lgkmcnt (ds_write)

        short8 af[4], bf[4];
#pragma unroll
        for (int mt = 0; mt < 4; ++mt) {
            int r = wm + mt * 16 + fr;
            af[mt] = *(const short8*)(As + r * 32 + ((fq ^ (r & 3)) * 8));
        }
#pragma unroll
        for (int nt = 0; nt < 4; ++nt) {
            int r = wn + nt * 16 + fr;
            bf[nt] = *(const short8*)(Bs + r * 32 + ((fq ^ (r & 3)) * 8));
        }
#pragma unroll
        for (int mt = 0; mt < 4; ++mt)
#pragma unroll
            for (int nt = 0; nt < 4; ++nt)
                acc[mt][nt] = __builtin_amdgcn_mfma_f32_16x16x32_bf16(af[mt], bf[nt],
                                                                      acc[mt][nt], 0, 0, 0);
    }

    // C/D layout: col = lane&15, row = quad*4 + reg
#pragma unroll
    for (int mt = 0; mt < 4; ++mt) {
#pragma unroll
        for (int i = 0; i < 4; ++i) {
            int gm = m0 + wm + mt * 16 + fq * 4 + i;
            if (gm >= M) continue;
#pragma unroll
            for (int nt = 0; nt < 4; ++nt) {
                int gn = n0 + wn + nt * 16 + fr;
                Cb[(size_t)gm * DD + gn] = f2b(acc[mt][nt][i]);
            }
        }
    }
}

// heterogeneous dispatch: atomic-free CSR fill (313 blocks) runs concurrently
// with GEMM1 (782 blocks) -- fill's ~10us hides under the GEMM
__global__ __launch_bounds__(256) void k_fill_gemm1(const int* __restrict__ src,
                                                    const int* __restrict__ he,
                                                    const int* __restrict__ off_n,
                                                    const int* __restrict__ off_e,
                                                    const int* __restrict__ rank_n,
                                                    const int* __restrict__ rank_e,
                                                    int* __restrict__ adj_n,
                                                    int* __restrict__ adj_e,
                                                    const float* __restrict__ x,
                                                    const unsigned short* __restrict__ w1b,
                                                    unsigned short* __restrict__ B1) {
    int bx = blockIdx.x;
    if (bx < CNTB) {
        int t  = bx * 256 + threadIdx.x;
        int e0 = t * 4;
        if (e0 >= NEDGE) return;
        int4 s  = *(const int4*)(src + e0);
        int4 h  = *(const int4*)(he + e0);
        int4 rn = *(const int4*)(rank_n + e0);
        int4 re = *(const int4*)(rank_e + e0);
        int on0 = off_n[s.x], on1 = off_n[s.y], on2 = off_n[s.z], on3 = off_n[s.w];
        int oe0 = off_e[h.x], oe1 = off_e[h.y], oe2 = off_e[h.z], oe3 = off_e[h.w];
        adj_n[on0 + rn.x] = h.x;
        adj_n[on1 + rn.y] = h.y;
        adj_n[on2 + rn.z] = h.z;
        adj_n[on3 + rn.w] = h.w;
        adj_e[oe0 + re.x] = s.x;
        adj_e[oe1 + re.y] = s.y;
        adj_e[oe2 + re.z] = s.z;
        adj_e[oe3 + re.w] = s.w;
        return;
    }
    int id = bx - CNTB;              // 0..781, n-tile fastest (A-tile L2 reuse)
    int nt = id & 1, mt = id >> 1;
    gemm128_body<true>((const void*)x, w1b, B1, NN, mt * 128, nt * 128);
}

// GEMM2 standalone; bx = n-tile (fast) so adjacent blocks share the A-tile
__global__ __launch_bounds__(256) void k_gemm2(const unsigned short* __restrict__ Av,
                                               const unsigned short* __restrict__ Wb,
                                               unsigned short* __restrict__ Cb) {
    gemm128_body<false>((const void*)Av, Wb, Cb, NN, blockIdx.y * 128, blockIdx.x * 128);
}

// ---------------- gather core: one 64-lane wave owns TWO rows --------------
// 8 B (4 bf16) per lane per row; both rows' 8-deep load batches issued before
// either accumulates (16 loads in flight/lane); degrees are wave-uniform ->
// zero divergence (the old 32-lane layout ran max(deg0,deg1) with half-masks).
static __device__ __forceinline__ void acc4(float* a, uint2 v) {
    a[0] += b2f_lo(v.x); a[1] += b2f_hi(v.x);
    a[2] += b2f_lo(v.y); a[3] += b2f_hi(v.y);
}
static __device__ __forceinline__ void gather2(const unsigned short* __restrict__ srcb,
                                               const int* __restrict__ adj,
                                               int b0, int e0, int b1, int e1,
                                               int ln, float* a0, float* a1) {
#pragma unroll
    for (int i = 0; i < 4; ++i) { a0[i] = 0.f; a1[i] = 0.f; }
    int i0 = b0, i1 = b1;
    while (i0 < e0 || i1 < e1) {
        uint2 v0[8], v1[8];
        bool act0 = i0 < e0, act1 = i1 < e1;   // wave-uniform
        if (act0) {
            int gg = adj[i0];
            int g[8];
            g[0] = gg;
#pragma unroll
            for (int j = 1; j < 8; ++j) g[j] = (i0 + j < e0) ? adj[i0 + j] : gg;
#pragma unroll
            for (int j = 0; j < 8; ++j)
                v0[j] = *(const uint2*)(srcb + (size_t)g[j] * DD + ln * 4);
        }
        if (act1) {
            int gg = adj[i1];
            int g[8];
            g[0] = gg;
#pragma unroll
            for (int j = 1; j < 8; ++j) g[j] = (i1 + j < e1) ? adj[i1 + j] : gg;
#pragma unroll
            for (int j = 0; j < 8; ++j)
                v1[j] = *(const uint2*)(srcb + (size_t)g[j] * DD + ln * 4);
        }
        if (act0) {
            acc4(a0, v0[0]);
#pragma unroll
            for (int j = 1; j < 8; ++j)
                if (i0 + j < e0) acc4(a0, v0[j]);
        }
        if (act1) {
            acc4(a1, v1[0]);
#pragma unroll
            for (int j = 1; j < 8; ++j)
                if (i1 + j < e1) acc4(a1, v1[j]);
        }
        i0 += 8; i1 += 8;
    }
}

__global__ __launch_bounds__(256) void k_gather_edge2(const unsigned short* __restrict__ xw,
                                                      unsigned short* __restrict__ ef,
                                                      const int* __restrict__ off,
                                                      const int* __restrict__ adj) {
    int tid = blockIdx.x * 256 + threadIdx.x;
    int wv = tid >> 6;
    int ln = tid & 63;
    int r0 = wv * 2, r1 = r0 + 1;
    if (r0 >= NHE) return;
    int b0 = off[r0], e0 = off[r0 + 1];
    int b1 = off[r1], e1 = off[r1 + 1];
    float a0[4], a1[4];
    gather2(xw, adj, b0, e0, b1, e1, ln, a0, a1);
    float s0 = (e0 > b0) ? 1.f / (float)(e0 - b0) : 0.f;
    float s1 = (e1 > b1) ? 1.f / (float)(e1 - b1) : 0.f;
    uint2 o0, o1;
    o0.x = pack2(a0[0] * s0, a0[1] * s0);
    o0.y = pack2(a0[2] * s0, a0[3] * s0);
    o1.x = pack2(a1[0] * s1, a1[1] * s1);
    o1.y = pack2(a1[2] * s1, a1[3] * s1);
    *(uint2*)(ef + (size_t)r0 * DD + ln * 4) = o0;
    *(uint2*)(ef + (size_t)r1 * DD + ln * 4) = o1;
}

__global__ __launch_bounds__(256) void k_gather_node_mid2(const unsigned short* __restrict__ ef,
                                                          unsigned short* __restrict__ h,
                                                          const int* __restrict__ off,
                                                          const int* __restrict__ adj,
                                                          const float* __restrict__ bias,
                                                          const float* __restrict__ aP) {
    int tid = blockIdx.x * 256 + threadIdx.x;
    int wv = tid >> 6;
    int ln = tid & 63;
    int r0 = wv * 2, r1 = r0 + 1;
    if (r0 >= NN) return;
    int b0 = off[r0], e0 = off[r0 + 1];
    int b1 = off[r1], e1 = off[r1 + 1];
    float a0[4], a1[4];
    gather2(ef, adj, b0, e0, b1, e1, ln, a0, a1);
    float s0 = (e0 > b0) ? 1.f / (float)(e0 - b0) : 0.f;
    float s1 = (e1 > b1) ? 1.f / (float)(e1 - b1) : 0.f;
    float al = *aP;
    float4 bb = ((const float4*)bias)[ln];
    float r[8];
    r[0] = a0[0] * s0 + bb.x; r[1] = a0[1] * s0 + bb.y;
    r[2] = a0[2] * s0 + bb.z; r[3] = a0[3] * s0 + bb.w;
    r[4] = a1[0] * s1 + bb.x; r[5] = a1[1] * s1 + bb.y;
    r[6] = a1[2] * s1 + bb.z; r[7] = a1[3] * s1 + bb.w;
#pragma unroll
    for (int i = 0; i < 8; ++i) r[i] = (r[i] >= 0.f) ? r[i] : al * r[i];
    uint2 o0, o1;
    o0.x = pack2(r[0], r[1]); o0.y = pack2(r[2], r[3]);
    o1.x = pack2(r[4], r[5]); o1.y = pack2(r[6], r[7]);
    *(uint2*)(h + (size_t)r0 * DD + ln * 4) = o0;
    *(uint2*)(h + (size_t)r1 * DD + ln * 4) = o1;
}

__global__ __launch_bounds__(256) void k_gather_node_final2(const unsigned short* __restrict__ ef,
                                                            const float* __restrict__ x,
                                                            float* __restrict__ out,
                                                            const int* __restrict__ off,
                                                            const int* __restrict__ adj,
                                                            const float* __restrict__ bias,
                                                            const float* __restrict__ aP) {
    int tid = blockIdx.x * 256 + threadIdx.x;
    int wv = tid >> 6;
    int ln = tid & 63;
    int r0 = wv * 2, r1 = r0 + 1;
    if (r0 >= NN) return;
    int b0 = off[r0], e0 = off[r0 + 1];
    int b1 = off[r1], e1 = off[r1 + 1];
    float a0[4], a1[4];
    gather2(ef, adj, b0, e0, b1, e1, ln, a0, a1);
    float s0 = (e0 > b0) ? 1.f / (float)(e0 - b0) : 0.f;
    float s1 = (e1 > b1) ? 1.f / (float)(e1 - b1) : 0.f;
    float al = *aP;
    float4 bb = ((const float4*)bias)[ln];
    float4 xv0 = *(const float4*)(x + (size_t)r0 * DD + ln * 4);
    float4 xv1 = *(const float4*)(x + (size_t)r1 * DD + ln * 4);
    float r[8];
    r[0] = a0[0] * s0 + bb.x + xv0.x; r[1] = a0[1] * s0 + bb.y + xv0.y;
    r[2] = a0[2] * s0 + bb.z + xv0.z; r[3] = a0[3] * s0 + bb.w + xv0.w;
    r[4] = a1[0] * s1 + bb.x + xv1.x; r[5] = a1[1] * s1 + bb.y + xv1.y;
    r[6] = a1[2] * s1 + bb.z + xv1.z; r[7] = a1[3] * s1 + bb.w + xv1.w;
#pragma unroll
    for (int i = 0; i < 8; ++i) r[i] = (r[i] >= 0.f) ? r[i] : al * r[i];
    *(float4*)(out + (size_t)r0 * DD + ln * 4) = make_float4(r[0], r[1], r[2], r[3]);
    *(float4*)(out + (size_t)r1 * DD + ln * 4) = make_float4(r[4], r[5], r[6], r[7]);
}

extern "C" void kernel_launch(void* const* d_in, const int* in_sizes, int n_in,
                              void* d_out, int out_size, void* d_ws, size_t ws_size,
                              hipStream_t stream) {
    const float* x       = (const float*)d_in[0];
    const float* W1      = (const float*)d_in[1];
    const float* b1      = (const float*)d_in[2];
    const float* W2      = (const float*)d_in[3];
    const float* b2      = (const float*)d_in[4];
    const float* prelu_a = (const float*)d_in[5];
    const int*   hei     = (const int*)d_in[6];
    const int* idx_src = hei;          // hei[0,:] node indices
    const int* idx_he  = hei + NEDGE;  // hei[1,:] hyperedge indices

    float* out = (float*)d_out;
    unsigned short* B1 = (unsigned short*)d_ws;           // [NN*DD] bf16
    unsigned short* B2 = B1 + (size_t)NN * DD;            // [NN*DD] bf16
    int* off_n  = (int*)(B2 + (size_t)NN * DD);           // NN+1
    int* off_e  = off_n + NN + 1;                         // NHE+1
    int* cnt_n  = off_e + NHE + 1;                        // NN
    int* cnt_e  = cnt_n + NN;                             // NHE
    int* adj_n  = cnt_e + NHE;                            // NEDGE
    int* adj_e  = adj_n + NEDGE;                          // NEDGE
    int* rank_n = adj_e + NEDGE;                          // NEDGE
    int* rank_e = rank_n + NEDGE;                         // NEDGE
    int* bsum   = rank_e + NEDGE;                         // 2*NBLK
    // d_out doubles as bf16 weight storage until the final kernel
    unsigned short* w1b = (unsigned short*)d_out;         // [DD*DD]
    unsigned short* w2b = w1b + DD * DD;                  // [DD*DD]

    const int gblocks = (NN / 2 * 64 + 255) / 256;        // 6250: 1 wave / 2 rows
    dim3 g2(DD / 128, (NN + 127) / 128);                  // GEMM2: n-tile fastest

    // ---- CSR build + weight cvt ----
    hipMemsetAsync(cnt_n, 0, sizeof(int) * (NN + NHE), stream);
    k_count_cvt<<<CNTB + 128, 256, 0, stream>>>(idx_src, idx_he, cnt_n, cnt_e,
                                                rank_n, rank_e, W1, W2, w1b, w2b);
    k_scan_a<<<2 * NBLK, 256, 0, stream>>>(cnt_n, cnt_e, bsum);
    k_scan_c<<<2 * NBLK, 256, 0, stream>>>(cnt_n, cnt_e, bsum, off_n, off_e);

    // ---- fill (CSR) || GEMM1 in one dispatch; then layer-1 gathers ----
    k_fill_gemm1<<<CNTB + 2 * ((NN + 127) / 128), 256, 0, stream>>>(
        idx_src, idx_he, off_n, off_e, rank_n, rank_e, adj_n, adj_e,
        x, w1b, B1);                                                             // B1 = bf16(x@W1^T)
    k_gather_edge2<<<gblocks, 256, 0, stream>>>(B1, B2, off_e, adj_e);           // B2 = ef1
    k_gather_node_mid2<<<gblocks, 256, 0, stream>>>(B2, B1, off_n, adj_n, b1, prelu_a); // B1 = h1

    // ---- layer 2 ----
    k_gemm2<<<g2, 256, 0, stream>>>(B1, w2b, B2);                                // B2 = bf16(h1@W2^T)
    k_gather_edge2<<<gblocks, 256, 0, stream>>>(B2, B1, off_e, adj_e);           // B1 = ef2
    k_gather_node_final2<<<gblocks, 256, 0, stream>>>(B1, x, out, off_n, adj_n, b2, prelu_a);
}